// Round 3
// baseline (558.776 us; speedup 1.0000x reference)
//
#include <hip/hip_runtime.h>
#include <hip/hip_bf16.h>

// B=8, T=2048, E=1024, D=DK*H=1024 (heads fused in the reference math)
//   Q=x@Wq, K=x@Wk, V=x@Wv            [16384 x 1024] bf16
//   energy[b] = Q_b K_b^T             fp32
//   lengths[b] = #nonzero rows of x[b] (== #nonzero of energy[b,0,:])
//   P = softmax(mask(energy)/8) bf16, written in place over energy rows
//   out[b] = P_b V_b                  [16384 x 1024] fp32
//
// GEMMs: bf16 NT (A row-major, B row-major = B^T) mfma_f32_16x16x32_bf16,
// 128x128 tile, BK=32, global_load_lds width=16 (m97 recipe).
//
// Workspace tiers (adaptive to ws_size so we NEVER silently skip work):
//  A (>=207.6MB): x16 32 | WT 6 | VT 32 | E 128 (fp32, all batches); Q,K in d_out.
//  B (>=140.5MB): x16 32 | WT 6 | VT 32 | Q 32 | K 32; E(2 batches, 32MB) reuses x16.
//  C (>= 39.9MB): WT 6 | per-batch x16/Q/K/VT (4MB each) | E 16MB; loop b=0..7.

typedef unsigned short u16;
typedef __bf16 bf16x8 __attribute__((ext_vector_type(8)));
typedef float f32x4 __attribute__((ext_vector_type(4)));

__device__ __forceinline__ u16 f2bf(float f) {
    union { float f; unsigned u; } x; x.f = f;
    unsigned r = x.u + 0x7FFFu + ((x.u >> 16) & 1u);   // RNE
    return (u16)(r >> 16);
}

__device__ __forceinline__ void gload_lds16(const void* g, void* l) {
    __builtin_amdgcn_global_load_lds(
        (const __attribute__((address_space(1))) unsigned*)g,
        (__attribute__((address_space(3))) unsigned*)l, 16, 0, 0);
}

// ---------------------------------------------------------------- cast x -> bf16
__global__ void cast_x(const float* __restrict__ x, u16* __restrict__ o) {
    int i = blockIdx.x * 256 + threadIdx.x;          // float4 index
    float4 v = ((const float4*)x)[i];
    ushort4 u;
    u.x = f2bf(v.x); u.y = f2bf(v.y); u.z = f2bf(v.z); u.w = f2bf(v.w);
    ((ushort4*)o)[i] = u;
}

// ------------------------------------------------- W[e][n] -> WT[n][e] bf16, x3
__global__ void transpose_cast_w(const float* __restrict__ Wq,
                                 const float* __restrict__ Wk,
                                 const float* __restrict__ Wv,
                                 u16* __restrict__ WT) {
    __shared__ float tile[32][33];
    const float* W = (blockIdx.z == 0) ? Wq : (blockIdx.z == 1) ? Wk : Wv;
    u16* T = WT + (size_t)blockIdx.z * 1048576;
    int n0 = blockIdx.x * 32, e0 = blockIdx.y * 32;
    int tx = threadIdx.x, ty = threadIdx.y;
#pragma unroll
    for (int j = 0; j < 4; ++j) {
        int e = ty + j * 8;
        tile[e][tx] = W[(size_t)(e0 + e) * 1024 + (n0 + tx)];
    }
    __syncthreads();
#pragma unroll
    for (int j = 0; j < 4; ++j) {
        int n = ty + j * 8;
        T[(size_t)(n0 + n) * 1024 + (e0 + tx)] = f2bf(tile[tx][n]);
    }
}

// ----------------------------------------------------- lengths[b] from x rows
__global__ void calc_lengths(const float* __restrict__ x, int* __restrict__ len) {
    int b = blockIdx.x, tid = threadIdx.x;
    int cnt = 0;
    for (int t = tid; t < 2048; t += 256) {
        float4 v = *(const float4*)(x + ((size_t)b * 2048 + t) * 1024);
        cnt += (v.x != 0.f || v.y != 0.f || v.z != 0.f || v.w != 0.f) ? 1 : 0;
    }
#pragma unroll
    for (int off = 32; off; off >>= 1) cnt += __shfl_xor(cnt, off);
    __shared__ int red[4];
    int wid = tid >> 6, lane = tid & 63;
    if (!lane) red[wid] = cnt;
    __syncthreads();
    if (tid == 0) len[b] = red[0] + red[1] + red[2] + red[3];
}

// ------------------------------------------------------------- bf16 NT GEMM
// C[m,n] = sum_k A[m,k]*B[n,k].  MODE 0: fp32 C. MODE 1: bf16 C.
// MODE 2: bf16 transposed store VT[d][t] (grow = b*2048+t within full run).
template <int MODE>
__global__ __launch_bounds__(256)
void gemm_bt(const u16* __restrict__ A, int lda, size_t sA,
             const u16* __restrict__ B, int ldb, size_t sB,
             void* __restrict__ Cv, int ldc, size_t sC, int Kdim) {
    __shared__ u16 As[128 * 32];
    __shared__ u16 Bs[128 * 32];
    const int tid = threadIdx.x;
    const int bz  = blockIdx.z;
    A += (size_t)bz * sA;
    B += (size_t)bz * sB;
    const size_t bm = (size_t)blockIdx.x * 128, bn = (size_t)blockIdx.y * 128;

    // staging: chunk c in [0,512): row=c>>2, col=(c&3)*8; thread does c=tid, tid+256
    const int r0 = tid >> 2;
    const int c0 = (tid & 3) * 8;
    const u16* a0 = A + (bm + r0) * (size_t)lda + c0;
    const u16* a1 = a0 + 64 * (size_t)lda;
    const u16* b0 = B + (bn + r0) * (size_t)ldb + c0;
    const u16* b1 = b0 + 64 * (size_t)ldb;
    u16* As0 = &As[tid * 8];
    u16* As1 = &As[(tid + 256) * 8];
    u16* Bs0 = &Bs[tid * 8];
    u16* Bs1 = &Bs[(tid + 256) * 8];

    const int wid = tid >> 6, lane = tid & 63;
    const int wrow = (wid >> 1) * 64, wcol = (wid & 1) * 64;
    const int q = lane >> 4, r = lane & 15;

    f32x4 acc[4][4] = {};

    for (int k0 = 0; k0 < Kdim; k0 += 32) {
        gload_lds16(a0 + k0, As0);
        gload_lds16(a1 + k0, As1);
        gload_lds16(b0 + k0, Bs0);
        gload_lds16(b1 + k0, Bs1);
        __syncthreads();
        bf16x8 af[4], bfr[4];
#pragma unroll
        for (int mt = 0; mt < 4; ++mt)
            af[mt] = *(const bf16x8*)&As[(wrow + mt * 16 + r) * 32 + q * 8];
#pragma unroll
        for (int nt = 0; nt < 4; ++nt)
            bfr[nt] = *(const bf16x8*)&Bs[(wcol + nt * 16 + r) * 32 + q * 8];
#pragma unroll
        for (int mt = 0; mt < 4; ++mt)
#pragma unroll
            for (int nt = 0; nt < 4; ++nt)
                acc[mt][nt] = __builtin_amdgcn_mfma_f32_16x16x32_bf16(
                    af[mt], bfr[nt], acc[mt][nt], 0, 0, 0);
        __syncthreads();
    }

    // C/D layout: col = lane&15, row = (lane>>4)*4 + i   [m89-verified]
    if (MODE == 0) {
        float* C = (float*)Cv + (size_t)bz * sC;
#pragma unroll
        for (int mt = 0; mt < 4; ++mt) {
            size_t row = bm + wrow + mt * 16 + q * 4;
#pragma unroll
            for (int nt = 0; nt < 4; ++nt) {
                size_t col = bn + wcol + nt * 16 + r;
#pragma unroll
                for (int i = 0; i < 4; ++i)
                    C[(row + i) * (size_t)ldc + col] = acc[mt][nt][i];
            }
        }
    } else if (MODE == 1) {
        u16* C = (u16*)Cv + (size_t)bz * sC;
#pragma unroll
        for (int mt = 0; mt < 4; ++mt) {
            size_t row = bm + wrow + mt * 16 + q * 4;
#pragma unroll
            for (int nt = 0; nt < 4; ++nt) {
                size_t col = bn + wcol + nt * 16 + r;
#pragma unroll
                for (int i = 0; i < 4; ++i)
                    C[(row + i) * (size_t)ldc + col] = f2bf(acc[mt][nt][i]);
            }
        }
    } else {  // MODE 2: VT[b][d][t] = V[b*2048+t][d]
        u16* C = (u16*)Cv;
#pragma unroll
        for (int mt = 0; mt < 4; ++mt) {
#pragma unroll
            for (int nt = 0; nt < 4; ++nt) {
                size_t gcol = bn + wcol + nt * 16 + r;   // d
#pragma unroll
                for (int i = 0; i < 4; ++i) {
                    size_t grow = bm + wrow + mt * 16 + q * 4 + i;  // b*2048+t
                    size_t b = grow >> 11, t = grow & 2047;
                    C[b * (size_t)(1024 * 2048) + gcol * 2048 + t] = f2bf(acc[mt][nt][i]);
                }
            }
        }
    }
}

// ---------------- masked softmax: fp32 row -> bf16 P in place (first half of row)
// lengths pointer is pre-offset by the caller; batch = row >> 11 within this launch.
__global__ void softmax_rows(float* __restrict__ E, const int* __restrict__ lengths) {
    int row = blockIdx.x;
    int len = lengths[row >> 11];
    float* e = E + (size_t)row * 2048;
    int tid = threadIdx.x;
    float4 v0 = ((const float4*)e)[tid];
    float4 v1 = ((const float4*)e)[tid + 256];
    float vals[8] = { v0.x, v0.y, v0.z, v0.w, v1.x, v1.y, v1.z, v1.w };
    int base0 = tid * 4, base1 = 1024 + tid * 4;
    int idx[8] = { base0, base0 + 1, base0 + 2, base0 + 3,
                   base1, base1 + 1, base1 + 2, base1 + 3 };

    float m = -3.4e38f;
#pragma unroll
    for (int j = 0; j < 8; ++j)
        if (idx[j] < len) m = fmaxf(m, vals[j]);
#pragma unroll
    for (int off = 32; off; off >>= 1) m = fmaxf(m, __shfl_xor(m, off));
    __shared__ float redm[4];
    __shared__ float reds[4];
    int wid = tid >> 6, lane = tid & 63;
    if (!lane) redm[wid] = m;
    __syncthreads();
    m = fmaxf(fmaxf(redm[0], redm[1]), fmaxf(redm[2], redm[3]));

    const float C = 0.18033688011112042f;   // log2(e)/8  (scale 1/sqrt(64))
    float p[8]; float s = 0.f;
#pragma unroll
    for (int j = 0; j < 8; ++j) {
        p[j] = (idx[j] < len) ? exp2f((vals[j] - m) * C) : 0.f;
        s += p[j];
    }
#pragma unroll
    for (int off = 32; off; off >>= 1) s += __shfl_xor(s, off);
    if (!lane) reds[wid] = s;
    __syncthreads();   // also orders: ALL initial loads complete before any write below
    s = reds[0] + reds[1] + reds[2] + reds[3];
    float rinv = 1.0f / s;

    u16* pr = (u16*)e;
    ushort4 o0, o1;
    o0.x = f2bf(p[0] * rinv); o0.y = f2bf(p[1] * rinv);
    o0.z = f2bf(p[2] * rinv); o0.w = f2bf(p[3] * rinv);
    o1.x = f2bf(p[4] * rinv); o1.y = f2bf(p[5] * rinv);
    o1.z = f2bf(p[6] * rinv); o1.w = f2bf(p[7] * rinv);
    ((ushort4*)pr)[tid]       = o0;
    ((ushort4*)pr)[tid + 256] = o1;
}

// ------------------------------------------------------------------ launch
extern "C" void kernel_launch(void* const* d_in, const int* in_sizes, int n_in,
                              void* d_out, int out_size, void* d_ws, size_t ws_size,
                              hipStream_t stream) {
    const float* x  = (const float*)d_in[0];
    const float* Wq = (const float*)d_in[1];
    const float* Wk = (const float*)d_in[2];
    const float* Wv = (const float*)d_in[3];
    float* out = (float*)d_out;
    char* ws = (char*)d_ws;

    const size_t SB  = 2097152;      // u16 elements per batch matrix (2048x1024)
    const size_t SBf = 4194304;      // fp32 elements per batch energy (2048x2048)

    if (ws_size >= 207618304ULL) {
        // ---- Tier A: full batch, Q/K in d_out, E fp32 all batches ----
        int* lengths = (int*)ws;
        u16* x16 = (u16*)(ws + 256);
        u16* WT  = (u16*)(ws + 33554688);
        u16* VT  = (u16*)(ws + 39846144);
        float* E = (float*)(ws + 73400576);          // 128 MB
        u16* Qb = (u16*)d_out;
        u16* Kb = Qb + 16777216;

        cast_x<<<dim3(16384), dim3(256), 0, stream>>>(x, x16);
        transpose_cast_w<<<dim3(32, 32, 3), dim3(32, 8), 0, stream>>>(Wq, Wk, Wv, WT);
        calc_lengths<<<dim3(8), dim3(256), 0, stream>>>(x, lengths);

        gemm_bt<1><<<dim3(128, 8, 1), 256, 0, stream>>>(x16, 1024, 0, WT,           1024, 0, Qb, 1024, 0, 1024);
        gemm_bt<1><<<dim3(128, 8, 1), 256, 0, stream>>>(x16, 1024, 0, WT + 1048576, 1024, 0, Kb, 1024, 0, 1024);
        gemm_bt<2><<<dim3(128, 8, 1), 256, 0, stream>>>(x16, 1024, 0, WT + 2097152, 1024, 0, VT, 0, 0, 1024);

        gemm_bt<0><<<dim3(16, 16, 8), 256, 0, stream>>>(Qb, 1024, SB, Kb, 1024, SB, E, 2048, SBf, 1024);
        softmax_rows<<<dim3(16384), dim3(256), 0, stream>>>(E, lengths);
        gemm_bt<0><<<dim3(16, 8, 8), 256, 0, stream>>>((const u16*)E, 4096, 2 * SBf,
                                                       VT, 2048, SB, out, 1024, SB, 2048);
    } else if (ws_size >= 140509440ULL) {
        // ---- Tier B: Q/K/VT in ws; energy 2 batches at a time reusing x16 region ----
        int* lengths = (int*)ws;
        u16* x16 = (u16*)(ws + 256);                 // 32 MB, freed after projections
        u16* WT  = (u16*)(ws + 33554688);
        u16* VT  = (u16*)(ws + 39846144);
        u16* Q   = (u16*)(ws + 73400576);
        u16* K   = (u16*)(ws + 106955008);
        float* E = (float*)(ws + 256);               // 32 MB (2 batches), overlaps x16

        cast_x<<<dim3(16384), dim3(256), 0, stream>>>(x, x16);
        transpose_cast_w<<<dim3(32, 32, 3), dim3(32, 8), 0, stream>>>(Wq, Wk, Wv, WT);
        calc_lengths<<<dim3(8), dim3(256), 0, stream>>>(x, lengths);

        gemm_bt<1><<<dim3(128, 8, 1), 256, 0, stream>>>(x16, 1024, 0, WT,           1024, 0, Q,  1024, 0, 1024);
        gemm_bt<1><<<dim3(128, 8, 1), 256, 0, stream>>>(x16, 1024, 0, WT + 1048576, 1024, 0, K,  1024, 0, 1024);
        gemm_bt<2><<<dim3(128, 8, 1), 256, 0, stream>>>(x16, 1024, 0, WT + 2097152, 1024, 0, VT, 0, 0, 1024);

        for (int p = 0; p < 4; ++p) {                // pairs of batches
            gemm_bt<0><<<dim3(16, 16, 2), 256, 0, stream>>>(Q + p * 2 * SB, 1024, SB,
                                                            K + p * 2 * SB, 1024, SB,
                                                            E, 2048, SBf, 1024);
            softmax_rows<<<dim3(4096), dim3(256), 0, stream>>>(E, lengths + p * 2);
            gemm_bt<0><<<dim3(16, 8, 2), 256, 0, stream>>>((const u16*)E, 4096, 2 * SBf,
                                                           VT + p * 2 * SB, 2048, SB,
                                                           out + p * 2 * SB, 1024, SB, 2048);
        }
    } else if (ws_size >= 39846144ULL) {
        // ---- Tier C: fully per-batch (safety net, ~38 MB) ----
        int* lengths = (int*)ws;
        u16* WT   = (u16*)(ws + 256);                // 6 MB
        u16* x16b = (u16*)(ws + 6291712);            // 4 MB
        u16* Qb   = (u16*)(ws + 10486016);           // 4 MB
        u16* Kb   = (u16*)(ws + 14680320);           // 4 MB
        u16* VTb  = (u16*)(ws + 18874624);           // 4 MB
        float* Eb = (float*)(ws + 23068928);         // 16 MB

        transpose_cast_w<<<dim3(32, 32, 3), dim3(32, 8), 0, stream>>>(Wq, Wk, Wv, WT);
        calc_lengths<<<dim3(8), dim3(256), 0, stream>>>(x, lengths);

        for (int b = 0; b < 8; ++b) {
            cast_x<<<dim3(2048), dim3(256), 0, stream>>>(x + (size_t)b * 2048 * 1024, x16b);
            gemm_bt<1><<<dim3(16, 8, 1), 256, 0, stream>>>(x16b, 1024, 0, WT,           1024, 0, Qb,  1024, 0, 1024);
            gemm_bt<1><<<dim3(16, 8, 1), 256, 0, stream>>>(x16b, 1024, 0, WT + 1048576, 1024, 0, Kb,  1024, 0, 1024);
            gemm_bt<2><<<dim3(16, 8, 1), 256, 0, stream>>>(x16b, 1024, 0, WT + 2097152, 1024, 0, VTb, 0, 0, 1024);
            gemm_bt<0><<<dim3(16, 16, 1), 256, 0, stream>>>(Qb, 1024, 0, Kb, 1024, 0, Eb, 2048, 0, 1024);
            softmax_rows<<<dim3(2048), dim3(256), 0, stream>>>(Eb, lengths + b);
            gemm_bt<0><<<dim3(16, 8, 1), 256, 0, stream>>>((const u16*)Eb, 4096, 0,
                                                           VTb, 2048, 0,
                                                           out + (size_t)b * SB, 1024, 0, 2048);
        }
    }
    // ws_size < 38 MB: nothing we can do — should not happen.
}

// Round 6
// 515.338 us; speedup vs baseline: 1.0843x; 1.0843x over previous
//
#include <hip/hip_runtime.h>
#include <hip/hip_bf16.h>

// B=8, T=2048, E=1024, D=DK*H=1024 (heads fused in reference math)
//   QKV = x @ [Wq|Wk|Wv]  fused GEMM   [16384 x 3072] bf16 (V stored transposed)
//   energy[b] = Q_b K_b^T              fp32 (bf16 E failed R4: absmax 0.0234>0.0233)
//   lengths[b] = #nonzero rows of x[b]
//   P = softmax(mask(energy)/8) bf16, in place over fp32 rows (one row per wave)
//   out[b] = P_b V_b                   fp32
//
// GEMM: bf16 NT, mfma_f32_16x16x32_bf16, 128x128 tile, BK=32,
// global_load_lds width=16 (m97 recipe). Q,K parked in d_out until PV.
// R5 bug fixed: softmax read (float4 chunks) and write (was us8 chunks) used
// different lane->column ownership, permuting P. Write is now ushort4 chunks
// with the identical (j*64+lane)*4+w mapping.
// ws = 207,618,304 B exactly (R3 Tier A proved this much is available):
//   lengths 256B | x16 32MB | WT 6MB (3072x1024) | VT 32MB | E 128MB fp32

typedef unsigned short u16;
typedef __bf16 bf16x8 __attribute__((ext_vector_type(8)));
typedef float f32x4 __attribute__((ext_vector_type(4)));

__device__ __forceinline__ u16 f2bf(float f) {
    union { float f; unsigned u; } x; x.f = f;
    unsigned r = x.u + 0x7FFFu + ((x.u >> 16) & 1u);   // RNE
    return (u16)(r >> 16);
}

__device__ __forceinline__ void gload_lds16(const void* g, void* l) {
    __builtin_amdgcn_global_load_lds(
        (const __attribute__((address_space(1))) unsigned*)g,
        (__attribute__((address_space(3))) unsigned*)l, 16, 0, 0);
}

// ---------------------------------------------------------------- cast x -> bf16
__global__ void cast_x(const float* __restrict__ x, u16* __restrict__ o) {
    int i = blockIdx.x * 256 + threadIdx.x;          // float4 index
    float4 v = ((const float4*)x)[i];
    ushort4 u;
    u.x = f2bf(v.x); u.y = f2bf(v.y); u.z = f2bf(v.z); u.w = f2bf(v.w);
    ((ushort4*)o)[i] = u;
}

// ------------------------------------------------- W[e][n] -> WT[n][e] bf16, x3
__global__ void transpose_cast_w(const float* __restrict__ Wq,
                                 const float* __restrict__ Wk,
                                 const float* __restrict__ Wv,
                                 u16* __restrict__ WT) {
    __shared__ float tile[32][33];
    const float* W = (blockIdx.z == 0) ? Wq : (blockIdx.z == 1) ? Wk : Wv;
    u16* T = WT + (size_t)blockIdx.z * 1048576;
    int n0 = blockIdx.x * 32, e0 = blockIdx.y * 32;
    int tx = threadIdx.x, ty = threadIdx.y;
#pragma unroll
    for (int j = 0; j < 4; ++j) {
        int e = ty + j * 8;
        tile[e][tx] = W[(size_t)(e0 + e) * 1024 + (n0 + tx)];
    }
    __syncthreads();
#pragma unroll
    for (int j = 0; j < 4; ++j) {
        int n = ty + j * 8;
        T[(size_t)(n0 + n) * 1024 + (e0 + tx)] = f2bf(tile[tx][n]);
    }
}

// ----------------------------------------------------- lengths[b] from x rows
__global__ void calc_lengths(const float* __restrict__ x, int* __restrict__ len) {
    int b = blockIdx.x, tid = threadIdx.x;
    int cnt = 0;
    for (int t = tid; t < 2048; t += 256) {
        float4 v = *(const float4*)(x + ((size_t)b * 2048 + t) * 1024);
        cnt += (v.x != 0.f || v.y != 0.f || v.z != 0.f || v.w != 0.f) ? 1 : 0;
    }
#pragma unroll
    for (int off = 32; off; off >>= 1) cnt += __shfl_xor(cnt, off);
    __shared__ int red[4];
    int wid = tid >> 6, lane = tid & 63;
    if (!lane) red[wid] = cnt;
    __syncthreads();
    if (tid == 0) len[b] = red[0] + red[1] + red[2] + red[3];
}

// ------------------------------------------------------------- bf16 NT GEMM
// C[m,n] = sum_k A[m,k]*B[n,k].
// MODE 0: fp32 C.
// MODE 3: fused-QKV routing: blockIdx.y 0-7 -> Q bf16 (Cv), 8-15 -> K bf16
//         (Cv + 16M elems), 16-23 -> VT transposed store (Cv2).
template <int MODE>
__global__ __launch_bounds__(256)
void gemm_bt(const u16* __restrict__ A, int lda, size_t sA,
             const u16* __restrict__ B, int ldb, size_t sB,
             void* __restrict__ Cv, void* __restrict__ Cv2,
             int ldc, size_t sC, int Kdim) {
    __shared__ u16 As[128 * 32];
    __shared__ u16 Bs[128 * 32];
    const int tid = threadIdx.x;
    const int bz  = blockIdx.z;
    A += (size_t)bz * sA;
    B += (size_t)bz * sB;
    const size_t bm = (size_t)blockIdx.x * 128, bn = (size_t)blockIdx.y * 128;

    // staging: chunk c in [0,512): row=c>>2, col=(c&3)*8; thread does c=tid, tid+256
    const int r0 = tid >> 2;
    const int c0 = (tid & 3) * 8;
    const u16* a0 = A + (bm + r0) * (size_t)lda + c0;
    const u16* a1 = a0 + 64 * (size_t)lda;
    const u16* b0 = B + (bn + r0) * (size_t)ldb + c0;
    const u16* b1 = b0 + 64 * (size_t)ldb;
    u16* As0 = &As[tid * 8];
    u16* As1 = &As[(tid + 256) * 8];
    u16* Bs0 = &Bs[tid * 8];
    u16* Bs1 = &Bs[(tid + 256) * 8];

    const int wid = tid >> 6, lane = tid & 63;
    const int wrow = (wid >> 1) * 64, wcol = (wid & 1) * 64;
    const int q = lane >> 4, r = lane & 15;

    f32x4 acc[4][4] = {};

    for (int k0 = 0; k0 < Kdim; k0 += 32) {
        gload_lds16(a0 + k0, As0);
        gload_lds16(a1 + k0, As1);
        gload_lds16(b0 + k0, Bs0);
        gload_lds16(b1 + k0, Bs1);
        __syncthreads();
        bf16x8 af[4], bfr[4];
#pragma unroll
        for (int mt = 0; mt < 4; ++mt)
            af[mt] = *(const bf16x8*)&As[(wrow + mt * 16 + r) * 32 + q * 8];
#pragma unroll
        for (int nt = 0; nt < 4; ++nt)
            bfr[nt] = *(const bf16x8*)&Bs[(wcol + nt * 16 + r) * 32 + q * 8];
#pragma unroll
        for (int mt = 0; mt < 4; ++mt)
#pragma unroll
            for (int nt = 0; nt < 4; ++nt)
                acc[mt][nt] = __builtin_amdgcn_mfma_f32_16x16x32_bf16(
                    af[mt], bfr[nt], acc[mt][nt], 0, 0, 0);
        __syncthreads();
    }

    // C/D layout: col = lane&15, row = (lane>>4)*4 + i   [m89-verified]
    if (MODE == 0) {
        float* C = (float*)Cv + (size_t)bz * sC;
#pragma unroll
        for (int mt = 0; mt < 4; ++mt) {
            size_t row = bm + wrow + mt * 16 + q * 4;
#pragma unroll
            for (int nt = 0; nt < 4; ++nt) {
                size_t col = bn + wcol + nt * 16 + r;
#pragma unroll
                for (int i = 0; i < 4; ++i)
                    C[(row + i) * (size_t)ldc + col] = acc[mt][nt][i];
            }
        }
    } else {  // MODE 3: fused QKV epilogue, region uniform per block
        int region = blockIdx.y >> 3;                 // 0:Q 1:K 2:V
        if (region < 2) {
            u16* C = (u16*)Cv + (size_t)region * 16777216;  // Q or K [16384x1024]
            size_t cb = bn - (size_t)region * 1024;
#pragma unroll
            for (int mt = 0; mt < 4; ++mt) {
                size_t row = bm + wrow + mt * 16 + q * 4;
#pragma unroll
                for (int nt = 0; nt < 4; ++nt) {
                    size_t col = cb + wcol + nt * 16 + r;
#pragma unroll
                    for (int i = 0; i < 4; ++i)
                        C[(row + i) * 1024 + col] = f2bf(acc[mt][nt][i]);
                }
            }
        } else {  // VT[b][d][t] = V[b*2048+t][d]
            u16* C = (u16*)Cv2;
#pragma unroll
            for (int mt = 0; mt < 4; ++mt) {
#pragma unroll
                for (int nt = 0; nt < 4; ++nt) {
                    size_t d = bn - 2048 + wcol + nt * 16 + r;
#pragma unroll
                    for (int i = 0; i < 4; ++i) {
                        size_t grow = bm + wrow + mt * 16 + q * 4 + i;  // b*2048+t
                        size_t b = grow >> 11, t = grow & 2047;
                        C[b * (size_t)(1024 * 2048) + d * 2048 + t] = f2bf(acc[mt][nt][i]);
                    }
                }
            }
        }
    }
}

// ------- masked softmax, ONE ROW PER WAVE: fp32 row in, bf16 P in place (row head)
// Read and write use the SAME lane->column mapping: column = (j*64+lane)*4 + w.
__global__ void softmax_rows_w(float* __restrict__ E, const int* __restrict__ lengths) {
    int row  = blockIdx.x * 4 + (threadIdx.x >> 6);   // 16384 rows, 4 waves/block
    int lane = threadIdx.x & 63;
    int len  = lengths[row >> 11];
    float* e = E + (size_t)row * 2048;

    float vals[32];
#pragma unroll
    for (int j = 0; j < 8; ++j) {
        float4 v = ((const float4*)e)[j * 64 + lane];
        vals[j * 4 + 0] = v.x; vals[j * 4 + 1] = v.y;
        vals[j * 4 + 2] = v.z; vals[j * 4 + 3] = v.w;
    }

    float m = -3.4e38f;
#pragma unroll
    for (int j = 0; j < 8; ++j) {
        int base = (j * 64 + lane) * 4;
#pragma unroll
        for (int w = 0; w < 4; ++w)
            if (base + w < len) m = fmaxf(m, vals[j * 4 + w]);
    }
#pragma unroll
    for (int off = 32; off; off >>= 1) m = fmaxf(m, __shfl_xor(m, off));

    const float C = 0.18033688011112042f;   // log2(e)/8  (scale 1/sqrt(64))
    float p[32]; float s = 0.f;
#pragma unroll
    for (int j = 0; j < 8; ++j) {
        int base = (j * 64 + lane) * 4;
#pragma unroll
        for (int w = 0; w < 4; ++w) {
            float v = (base + w < len) ? exp2f((vals[j * 4 + w] - m) * C) : 0.f;
            p[j * 4 + w] = v;
            s += v;
        }
    }
#pragma unroll
    for (int off = 32; off; off >>= 1) s += __shfl_xor(s, off);
    float rinv = 1.0f / s;

    // bf16 P over the first half of the fp32 row; ushort4 chunk (j*64+lane)
    // covers u16 indices (j*64+lane)*4+w — identical mapping to the read.
    u16* pr = (u16*)e;
#pragma unroll
    for (int j = 0; j < 8; ++j) {
        ushort4 o;
        o.x = f2bf(p[j * 4 + 0] * rinv);
        o.y = f2bf(p[j * 4 + 1] * rinv);
        o.z = f2bf(p[j * 4 + 2] * rinv);
        o.w = f2bf(p[j * 4 + 3] * rinv);
        ((ushort4*)pr)[j * 64 + lane] = o;
    }
}

// ------------------------------------------------------------------ launch
extern "C" void kernel_launch(void* const* d_in, const int* in_sizes, int n_in,
                              void* d_out, int out_size, void* d_ws, size_t ws_size,
                              hipStream_t stream) {
    const float* x  = (const float*)d_in[0];
    const float* Wq = (const float*)d_in[1];
    const float* Wk = (const float*)d_in[2];
    const float* Wv = (const float*)d_in[3];
    float* out = (float*)d_out;
    char* ws = (char*)d_ws;

    const size_t SB  = 2097152;      // elems per batch [2048x1024]
    const size_t SBf = 4194304;      // fp32 elems per batch energy [2048x2048]

    // ws: lengths 256B | x16 32MB | WT 6MB | VT 32MB | E 128MB fp32 = 207,618,304 B
    if (ws_size < 207618304ULL) return;              // == R3 Tier A proven budget
    int* lengths = (int*)ws;
    u16* x16 = (u16*)(ws + 256);
    u16* WT  = (u16*)(ws + 33554688);
    u16* VT  = (u16*)(ws + 39846144);
    float* E = (float*)(ws + 73400576);
    u16* Qb  = (u16*)d_out;                          // Q,K parked in d_out (64 MiB)
    u16* Kb  = Qb + 16777216;

    cast_x<<<dim3(16384), dim3(256), 0, stream>>>(x, x16);
    transpose_cast_w<<<dim3(32, 32, 3), dim3(32, 8), 0, stream>>>(Wq, Wk, Wv, WT);
    calc_lengths<<<dim3(8), dim3(256), 0, stream>>>(x, lengths);

    // fused QKV: x16[16384x1024] @ WT[3072x1024]^T -> Q,K (d_out) + VT (ws)
    gemm_bt<3><<<dim3(128, 24, 1), 256, 0, stream>>>(x16, 1024, 0, WT, 1024, 0,
                                                     Qb, VT, 0, 0, 1024);

    // energy[b] = Q_b K_b^T -> fp32 E
    gemm_bt<0><<<dim3(16, 16, 8), 256, 0, stream>>>(Qb, 1024, SB, Kb, 1024, SB,
                                                    E, nullptr, 2048, SBf, 1024);

    // masked softmax -> bf16 P in place (one row per wave)
    softmax_rows_w<<<dim3(4096), dim3(256), 0, stream>>>(E, lengths);

    // out[b] = P_b V_b = P_b (VT_b)^T   (A = bf16 P rows, u16-stride 4096)
    gemm_bt<0><<<dim3(16, 8, 8), 256, 0, stream>>>((const u16*)E, 4096, 2 * SBf,
                                                   VT, 2048, SB,
                                                   out, nullptr, 1024, SB, 2048);
}

// Round 7
// 499.188 us; speedup vs baseline: 1.1194x; 1.0324x over previous
//
#include <hip/hip_runtime.h>
#include <hip/hip_bf16.h>

// B=8, T=2048, E=1024, D=DK*H=1024 (heads fused in reference math)
//   QKV = x @ [Wq|Wk|Wv]  fused GEMM  [16384 x 3072] bf16 (V stored transposed);
//         m-blocks entirely beyond len[b] skip compute and store zeros (x rows = 0).
//   energy[b] = Q_b K_b^T             fp16 (bf16 failed R4; fp16 has 8x finer ulp);
//         n-blocks with bn >= len[b] skipped entirely (softmax masks by index).
//   lengths[b] = #nonzero rows of x[b]
//   P = softmax(mask(energy)/8) bf16 in place over fp16 rows (one row per wave)
//   out[b] = P_b V_b                  fp32; K-loop clamped to round32(len[b])
//           (P cols in [len, round32(len)) are softmax-written zeros).
//
// GEMM: bf16 NT, mfma_f32_16x16x32_bf16, 128x128 tile, BK=32,
// global_load_lds width=16 (m97 recipe). Q,K parked in d_out until PV.
// ws = 140,509,440 B: lengths 256B | x16 32MB | WT 6MB | VT 32MB | E 64MB fp16.

typedef unsigned short u16;
typedef __bf16 bf16x8 __attribute__((ext_vector_type(8)));
typedef float f32x4 __attribute__((ext_vector_type(4)));
typedef unsigned short us8 __attribute__((ext_vector_type(8)));

__device__ __forceinline__ u16 f2bf(float f) {
    union { float f; unsigned u; } x; x.f = f;
    unsigned r = x.u + 0x7FFFu + ((x.u >> 16) & 1u);   // RNE
    return (u16)(r >> 16);
}
__device__ __forceinline__ u16 f2h(float f) {
    union { _Float16 h; u16 u; } c; c.h = (_Float16)f;
    return c.u;
}
__device__ __forceinline__ float h2f(u16 b) {
    union { u16 u; _Float16 h; } c; c.u = b;
    return (float)c.h;
}

__device__ __forceinline__ void gload_lds16(const void* g, void* l) {
    __builtin_amdgcn_global_load_lds(
        (const __attribute__((address_space(1))) unsigned*)g,
        (__attribute__((address_space(3))) unsigned*)l, 16, 0, 0);
}

// ---------------------------------------------------------------- cast x -> bf16
__global__ void cast_x(const float* __restrict__ x, u16* __restrict__ o) {
    int i = blockIdx.x * 256 + threadIdx.x;          // float4 index
    float4 v = ((const float4*)x)[i];
    ushort4 u;
    u.x = f2bf(v.x); u.y = f2bf(v.y); u.z = f2bf(v.z); u.w = f2bf(v.w);
    ((ushort4*)o)[i] = u;
}

// ------------------------------------------------- W[e][n] -> WT[n][e] bf16, x3
__global__ void transpose_cast_w(const float* __restrict__ Wq,
                                 const float* __restrict__ Wk,
                                 const float* __restrict__ Wv,
                                 u16* __restrict__ WT) {
    __shared__ float tile[32][33];
    const float* W = (blockIdx.z == 0) ? Wq : (blockIdx.z == 1) ? Wk : Wv;
    u16* T = WT + (size_t)blockIdx.z * 1048576;
    int n0 = blockIdx.x * 32, e0 = blockIdx.y * 32;
    int tx = threadIdx.x, ty = threadIdx.y;
#pragma unroll
    for (int j = 0; j < 4; ++j) {
        int e = ty + j * 8;
        tile[e][tx] = W[(size_t)(e0 + e) * 1024 + (n0 + tx)];
    }
    __syncthreads();
#pragma unroll
    for (int j = 0; j < 4; ++j) {
        int n = ty + j * 8;
        T[(size_t)(n0 + n) * 1024 + (e0 + tx)] = f2bf(tile[tx][n]);
    }
}

// ----------------------------------------------------- lengths[b] from x rows
__global__ void calc_lengths(const float* __restrict__ x, int* __restrict__ len) {
    int b = blockIdx.x, tid = threadIdx.x;
    int cnt = 0;
    for (int t = tid; t < 2048; t += 256) {
        float4 v = *(const float4*)(x + ((size_t)b * 2048 + t) * 1024);
        cnt += (v.x != 0.f || v.y != 0.f || v.z != 0.f || v.w != 0.f) ? 1 : 0;
    }
#pragma unroll
    for (int off = 32; off; off >>= 1) cnt += __shfl_xor(cnt, off);
    __shared__ int red[4];
    int wid = tid >> 6, lane = tid & 63;
    if (!lane) red[wid] = cnt;
    __syncthreads();
    if (tid == 0) len[b] = red[0] + red[1] + red[2] + red[3];
}

// ------------------------------------------------------------- bf16 NT GEMM
// C[m,n] = sum_k A[m,k]*B[n,k].
// MODE 3: fused-QKV routing (y 0-7 Q, 8-15 K -> Cv; 16-23 VT transposed -> Cv2);
//         m-blocks with t_start >= len[b] skip the K-loop (store zeros).
// MODE 4: energy, fp16 store; block returns if bn >= len[bz].
// MODE 5: PV, fp32 store; K-loop clamped to round32(len[bz]).
template <int MODE>
__global__ __launch_bounds__(256)
void gemm_bt(const u16* __restrict__ A, int lda, size_t sA,
             const u16* __restrict__ B, int ldb, size_t sB,
             void* __restrict__ Cv, void* __restrict__ Cv2,
             int ldc, size_t sC, int Kdim, const int* __restrict__ lenp) {
    __shared__ u16 As[128 * 32];
    __shared__ u16 Bs[128 * 32];
    const int tid = threadIdx.x;
    const int bz  = blockIdx.z;
    A += (size_t)bz * sA;
    B += (size_t)bz * sB;
    const size_t bm = (size_t)blockIdx.x * 128, bn = (size_t)blockIdx.y * 128;

    bool skip_loop = false;
    int kEnd = Kdim;
    if (MODE == 3) {
        int lenz = lenp[bm >> 11];
        skip_loop = ((int)(bm & 2047) >= lenz);      // whole tile rows are zero
    } else if (MODE == 4) {
        int lenz = lenp[bz];
        if ((int)bn >= lenz) return;                 // cols fully masked: E unread
    } else if (MODE == 5) {
        int lenz = lenp[bz];
        int r32 = (lenz + 31) & ~31;
        kEnd = r32 < Kdim ? r32 : Kdim;              // P cols >= len are zeros
    }

    // staging: chunk c in [0,512): row=c>>2, col=(c&3)*8; thread does c=tid, tid+256
    const int r0 = tid >> 2;
    const int c0 = (tid & 3) * 8;
    const u16* a0 = A + (bm + r0) * (size_t)lda + c0;
    const u16* a1 = a0 + 64 * (size_t)lda;
    const u16* b0 = B + (bn + r0) * (size_t)ldb + c0;
    const u16* b1 = b0 + 64 * (size_t)ldb;
    u16* As0 = &As[tid * 8];
    u16* As1 = &As[(tid + 256) * 8];
    u16* Bs0 = &Bs[tid * 8];
    u16* Bs1 = &Bs[(tid + 256) * 8];

    const int wid = tid >> 6, lane = tid & 63;
    const int wrow = (wid >> 1) * 64, wcol = (wid & 1) * 64;
    const int q = lane >> 4, r = lane & 15;

    f32x4 acc[4][4] = {};

    if (!skip_loop) {
        for (int k0 = 0; k0 < kEnd; k0 += 32) {
            gload_lds16(a0 + k0, As0);
            gload_lds16(a1 + k0, As1);
            gload_lds16(b0 + k0, Bs0);
            gload_lds16(b1 + k0, Bs1);
            __syncthreads();
            bf16x8 af[4], bfr[4];
#pragma unroll
            for (int mt = 0; mt < 4; ++mt)
                af[mt] = *(const bf16x8*)&As[(wrow + mt * 16 + r) * 32 + q * 8];
#pragma unroll
            for (int nt = 0; nt < 4; ++nt)
                bfr[nt] = *(const bf16x8*)&Bs[(wcol + nt * 16 + r) * 32 + q * 8];
#pragma unroll
            for (int mt = 0; mt < 4; ++mt)
#pragma unroll
                for (int nt = 0; nt < 4; ++nt)
                    acc[mt][nt] = __builtin_amdgcn_mfma_f32_16x16x32_bf16(
                        af[mt], bfr[nt], acc[mt][nt], 0, 0, 0);
            __syncthreads();
        }
    }

    // C/D layout: col = lane&15, row = (lane>>4)*4 + i   [m89-verified]
    if (MODE == 5) {
        float* C = (float*)Cv + (size_t)bz * sC;
#pragma unroll
        for (int mt = 0; mt < 4; ++mt) {
            size_t row = bm + wrow + mt * 16 + q * 4;
#pragma unroll
            for (int nt = 0; nt < 4; ++nt) {
                size_t col = bn + wcol + nt * 16 + r;
#pragma unroll
                for (int i = 0; i < 4; ++i)
                    C[(row + i) * (size_t)ldc + col] = acc[mt][nt][i];
            }
        }
    } else if (MODE == 4) {
        u16* C = (u16*)Cv + (size_t)bz * sC;
#pragma unroll
        for (int mt = 0; mt < 4; ++mt) {
            size_t row = bm + wrow + mt * 16 + q * 4;
#pragma unroll
            for (int nt = 0; nt < 4; ++nt) {
                size_t col = bn + wcol + nt * 16 + r;
#pragma unroll
                for (int i = 0; i < 4; ++i)
                    C[(row + i) * (size_t)ldc + col] = f2h(acc[mt][nt][i]);
            }
        }
    } else {  // MODE 3: fused QKV epilogue, region uniform per block
        int region = blockIdx.y >> 3;                 // 0:Q 1:K 2:V
        if (region < 2) {
            u16* C = (u16*)Cv + (size_t)region * 16777216;  // Q or K [16384x1024]
            size_t cb = bn - (size_t)region * 1024;
#pragma unroll
            for (int mt = 0; mt < 4; ++mt) {
                size_t row = bm + wrow + mt * 16 + q * 4;
#pragma unroll
                for (int nt = 0; nt < 4; ++nt) {
                    size_t col = cb + wcol + nt * 16 + r;
#pragma unroll
                    for (int i = 0; i < 4; ++i)
                        C[(row + i) * 1024 + col] = f2bf(acc[mt][nt][i]);
                }
            }
        } else {  // VT[b][d][t] = V[b*2048+t][d]
            u16* C = (u16*)Cv2;
#pragma unroll
            for (int mt = 0; mt < 4; ++mt) {
#pragma unroll
                for (int nt = 0; nt < 4; ++nt) {
                    size_t d = bn - 2048 + wcol + nt * 16 + r;
#pragma unroll
                    for (int i = 0; i < 4; ++i) {
                        size_t grow = bm + wrow + mt * 16 + q * 4 + i;  // b*2048+t
                        size_t b = grow >> 11, t = grow & 2047;
                        C[b * (size_t)(1024 * 2048) + d * 2048 + t] = f2bf(acc[mt][nt][i]);
                    }
                }
            }
        }
    }
}

// ---- masked softmax, ONE ROW PER WAVE: fp16 row in, bf16 P in place (full row)
// Read and write both use us8 chunks: chunk c = j*64+lane covers cols c*8..c*8+7.
__global__ void softmax_rows_w(u16* __restrict__ E, const int* __restrict__ lengths) {
    int row  = blockIdx.x * 4 + (threadIdx.x >> 6);   // 16384 rows, 4 waves/block
    int lane = threadIdx.x & 63;
    int len  = lengths[row >> 11];
    u16* e = E + (size_t)row * 2048;

    float vals[32];
#pragma unroll
    for (int j = 0; j < 4; ++j) {
        us8 v = ((const us8*)e)[j * 64 + lane];
#pragma unroll
        for (int w = 0; w < 8; ++w) vals[j * 8 + w] = h2f(v[w]);
    }

    float m = -3.4e38f;
#pragma unroll
    for (int j = 0; j < 4; ++j) {
        int base = (j * 64 + lane) * 8;
#pragma unroll
        for (int w = 0; w < 8; ++w)
            if (base + w < len) m = fmaxf(m, vals[j * 8 + w]);
    }
#pragma unroll
    for (int off = 32; off; off >>= 1) m = fmaxf(m, __shfl_xor(m, off));

    const float C = 0.18033688011112042f;   // log2(e)/8  (scale 1/sqrt(64))
    float p[32]; float s = 0.f;
#pragma unroll
    for (int j = 0; j < 4; ++j) {
        int base = (j * 64 + lane) * 8;
#pragma unroll
        for (int w = 0; w < 8; ++w) {
            float v = (base + w < len) ? exp2f((vals[j * 8 + w] - m) * C) : 0.f;
            p[j * 8 + w] = v;
            s += v;
        }
    }
#pragma unroll
    for (int off = 32; off; off >>= 1) s += __shfl_xor(s, off);
    float rinv = 1.0f / s;

    // bf16 P over the fp16 row, identical chunk mapping as the read
#pragma unroll
    for (int j = 0; j < 4; ++j) {
        us8 o;
#pragma unroll
        for (int w = 0; w < 8; ++w) o[w] = f2bf(p[j * 8 + w] * rinv);
        ((us8*)e)[j * 64 + lane] = o;
    }
}

// ------------------------------------------------------------------ launch
extern "C" void kernel_launch(void* const* d_in, const int* in_sizes, int n_in,
                              void* d_out, int out_size, void* d_ws, size_t ws_size,
                              hipStream_t stream) {
    const float* x  = (const float*)d_in[0];
    const float* Wq = (const float*)d_in[1];
    const float* Wk = (const float*)d_in[2];
    const float* Wv = (const float*)d_in[3];
    float* out = (float*)d_out;
    char* ws = (char*)d_ws;

    const size_t SB  = 2097152;      // u16 elems per batch [2048x1024]
    const size_t SBe = 4194304;      // u16 elems per batch energy [2048x2048]

    // ws: lengths 256B | x16 32MB | WT 6MB | VT 32MB | E 64MB fp16 = 140,509,440 B
    if (ws_size < 140509440ULL) return;              // R3 proved >=207.6MB available
    int* lengths = (int*)ws;
    u16* x16 = (u16*)(ws + 256);
    u16* WT  = (u16*)(ws + 33554688);
    u16* VT  = (u16*)(ws + 39846144);
    u16* E   = (u16*)(ws + 73400576);
    u16* Qb  = (u16*)d_out;                          // Q,K parked in d_out (64 MiB)
    u16* Kb  = Qb + 16777216;

    cast_x<<<dim3(16384), dim3(256), 0, stream>>>(x, x16);
    transpose_cast_w<<<dim3(32, 32, 3), dim3(32, 8), 0, stream>>>(Wq, Wk, Wv, WT);
    calc_lengths<<<dim3(8), dim3(256), 0, stream>>>(x, lengths);

    // fused QKV: x16[16384x1024] @ WT[3072x1024]^T -> Q,K (d_out) + VT (ws)
    gemm_bt<3><<<dim3(128, 24, 1), 256, 0, stream>>>(x16, 1024, 0, WT, 1024, 0,
                                                     Qb, VT, 0, 0, 1024, lengths);

    // energy[b] = Q_b K_b^T -> fp16 E; blocks with bn >= len[b] skipped
    gemm_bt<4><<<dim3(16, 16, 8), 256, 0, stream>>>(Qb, 1024, SB, Kb, 1024, SB,
                                                    E, nullptr, 2048, SBe, 1024, lengths);

    // masked softmax -> bf16 P in place (one row per wave)
    softmax_rows_w<<<dim3(4096), dim3(256), 0, stream>>>(E, lengths);

    // out[b] = P_b V_b = P_b (VT_b)^T; K clamped to round32(len[b])
    gemm_bt<5><<<dim3(16, 8, 8), 256, 0, stream>>>(E, 2048, SBe, VT, 2048, SB,
                                                   out, nullptr, 1024, SB, 2048, lengths);
}

// Round 8
// 417.275 us; speedup vs baseline: 1.3391x; 1.1963x over previous
//
#include <hip/hip_runtime.h>
#include <hip/hip_bf16.h>

// B=8, T=2048, E=1024, D=DK*H=1024 (heads fused in reference math)
//   QKV = x @ [Wq|Wk|Wv]  fused GEMM  [16384 x 3072] bf16 (V stored transposed);
//         m-blocks entirely beyond len[b] skip compute and store zeros (x rows = 0).
//   energy[b] = Q_b K_b^T             fp16; n-blocks with bn >= len[b] skipped.
//   lengths[b] = #nonzero rows of x[b]
//   P = softmax(mask(energy)/8) bf16 in place over fp16 rows (one row per wave)
//   out[b] = P_b V_b                  fp32; K-loop clamped to round32(len[b]).
//
// GEMM: bf16 NT, mfma_f32_16x16x32_bf16, 128x128 tile, BK=32,
// global_load_lds width=16 (m97 recipe). Q,K parked in d_out until PV.
// R8: __launch_bounds__(256,3) pins >=3 blocks/CU (R7's QKV hit VGPR 108 ->
// 2 blocks/CU, 188us). VT epilogue: block-uniform batch base + ushort4 stores.
// ws = 140,509,440 B: lengths 256B | x16 32MB | WT 6MB | VT 32MB | E 64MB fp16.

typedef unsigned short u16;
typedef __bf16 bf16x8 __attribute__((ext_vector_type(8)));
typedef float f32x4 __attribute__((ext_vector_type(4)));
typedef unsigned short us8 __attribute__((ext_vector_type(8)));

__device__ __forceinline__ u16 f2bf(float f) {
    union { float f; unsigned u; } x; x.f = f;
    unsigned r = x.u + 0x7FFFu + ((x.u >> 16) & 1u);   // RNE
    return (u16)(r >> 16);
}
__device__ __forceinline__ u16 f2h(float f) {
    union { _Float16 h; u16 u; } c; c.h = (_Float16)f;
    return c.u;
}
__device__ __forceinline__ float h2f(u16 b) {
    union { u16 u; _Float16 h; } c; c.u = b;
    return (float)c.h;
}

__device__ __forceinline__ void gload_lds16(const void* g, void* l) {
    __builtin_amdgcn_global_load_lds(
        (const __attribute__((address_space(1))) unsigned*)g,
        (__attribute__((address_space(3))) unsigned*)l, 16, 0, 0);
}

// ---------------------------------------------------------------- cast x -> bf16
__global__ void cast_x(const float* __restrict__ x, u16* __restrict__ o) {
    int i = blockIdx.x * 256 + threadIdx.x;          // float4 index
    float4 v = ((const float4*)x)[i];
    ushort4 u;
    u.x = f2bf(v.x); u.y = f2bf(v.y); u.z = f2bf(v.z); u.w = f2bf(v.w);
    ((ushort4*)o)[i] = u;
}

// ------------------------------------------------- W[e][n] -> WT[n][e] bf16, x3
__global__ void transpose_cast_w(const float* __restrict__ Wq,
                                 const float* __restrict__ Wk,
                                 const float* __restrict__ Wv,
                                 u16* __restrict__ WT) {
    __shared__ float tile[32][33];
    const float* W = (blockIdx.z == 0) ? Wq : (blockIdx.z == 1) ? Wk : Wv;
    u16* T = WT + (size_t)blockIdx.z * 1048576;
    int n0 = blockIdx.x * 32, e0 = blockIdx.y * 32;
    int tx = threadIdx.x, ty = threadIdx.y;
#pragma unroll
    for (int j = 0; j < 4; ++j) {
        int e = ty + j * 8;
        tile[e][tx] = W[(size_t)(e0 + e) * 1024 + (n0 + tx)];
    }
    __syncthreads();
#pragma unroll
    for (int j = 0; j < 4; ++j) {
        int n = ty + j * 8;
        T[(size_t)(n0 + n) * 1024 + (e0 + tx)] = f2bf(tile[tx][n]);
    }
}

// ----------------------------------------------------- lengths[b] from x rows
__global__ void calc_lengths(const float* __restrict__ x, int* __restrict__ len) {
    int b = blockIdx.x, tid = threadIdx.x;
    int cnt = 0;
    for (int t = tid; t < 2048; t += 256) {
        float4 v = *(const float4*)(x + ((size_t)b * 2048 + t) * 1024);
        cnt += (v.x != 0.f || v.y != 0.f || v.z != 0.f || v.w != 0.f) ? 1 : 0;
    }
#pragma unroll
    for (int off = 32; off; off >>= 1) cnt += __shfl_xor(cnt, off);
    __shared__ int red[4];
    int wid = tid >> 6, lane = tid & 63;
    if (!lane) red[wid] = cnt;
    __syncthreads();
    if (tid == 0) len[b] = red[0] + red[1] + red[2] + red[3];
}

// ------------------------------------------------------------- bf16 NT GEMM
// C[m,n] = sum_k A[m,k]*B[n,k].
// MODE 3: fused-QKV routing (y 0-7 Q, 8-15 K -> Cv; 16-23 VT transposed -> Cv2);
//         m-blocks with t_start >= len[b] skip the K-loop (store zeros).
// MODE 4: energy, fp16 store; block returns if bn >= len[bz].
// MODE 5: PV, fp32 store; K-loop clamped to round32(len[bz]).
template <int MODE>
__global__ __launch_bounds__(256, 3)   // pin >=3 blocks/CU (R7 regressed to 2)
void gemm_bt(const u16* __restrict__ A, int lda, size_t sA,
             const u16* __restrict__ B, int ldb, size_t sB,
             void* __restrict__ Cv, void* __restrict__ Cv2,
             int ldc, size_t sC, int Kdim, const int* __restrict__ lenp) {
    __shared__ u16 As[128 * 32];
    __shared__ u16 Bs[128 * 32];
    const int tid = threadIdx.x;
    const int bz  = blockIdx.z;
    A += (size_t)bz * sA;
    B += (size_t)bz * sB;
    const size_t bm = (size_t)blockIdx.x * 128, bn = (size_t)blockIdx.y * 128;

    bool skip_loop = false;
    int kEnd = Kdim;
    if (MODE == 3) {
        int lenz = lenp[bm >> 11];
        skip_loop = ((int)(bm & 2047) >= lenz);      // whole tile rows are zero
    } else if (MODE == 4) {
        int lenz = lenp[bz];
        if ((int)bn >= lenz) return;                 // cols fully masked: E unread
    } else if (MODE == 5) {
        int lenz = lenp[bz];
        int r32 = (lenz + 31) & ~31;
        kEnd = r32 < Kdim ? r32 : Kdim;              // P cols >= len are zeros
    }

    // staging: chunk c in [0,512): row=c>>2, col=(c&3)*8; thread does c=tid, tid+256
    const int r0 = tid >> 2;
    const int c0 = (tid & 3) * 8;
    const u16* a0 = A + (bm + r0) * (size_t)lda + c0;
    const u16* a1 = a0 + 64 * (size_t)lda;
    const u16* b0 = B + (bn + r0) * (size_t)ldb + c0;
    const u16* b1 = b0 + 64 * (size_t)ldb;
    u16* As0 = &As[tid * 8];
    u16* As1 = &As[(tid + 256) * 8];
    u16* Bs0 = &Bs[tid * 8];
    u16* Bs1 = &Bs[(tid + 256) * 8];

    const int wid = tid >> 6, lane = tid & 63;
    const int wrow = (wid >> 1) * 64, wcol = (wid & 1) * 64;
    const int q = lane >> 4, r = lane & 15;

    f32x4 acc[4][4] = {};

    if (!skip_loop) {
        for (int k0 = 0; k0 < kEnd; k0 += 32) {
            gload_lds16(a0 + k0, As0);
            gload_lds16(a1 + k0, As1);
            gload_lds16(b0 + k0, Bs0);
            gload_lds16(b1 + k0, Bs1);
            __syncthreads();
            bf16x8 af[4], bfr[4];
#pragma unroll
            for (int mt = 0; mt < 4; ++mt)
                af[mt] = *(const bf16x8*)&As[(wrow + mt * 16 + r) * 32 + q * 8];
#pragma unroll
            for (int nt = 0; nt < 4; ++nt)
                bfr[nt] = *(const bf16x8*)&Bs[(wcol + nt * 16 + r) * 32 + q * 8];
#pragma unroll
            for (int mt = 0; mt < 4; ++mt)
#pragma unroll
                for (int nt = 0; nt < 4; ++nt)
                    acc[mt][nt] = __builtin_amdgcn_mfma_f32_16x16x32_bf16(
                        af[mt], bfr[nt], acc[mt][nt], 0, 0, 0);
            __syncthreads();
        }
    }

    // C/D layout: col = lane&15, row = (lane>>4)*4 + i   [m89-verified]
    if (MODE == 5) {
        float* C = (float*)Cv + (size_t)bz * sC;
#pragma unroll
        for (int mt = 0; mt < 4; ++mt) {
            size_t row = bm + wrow + mt * 16 + q * 4;
#pragma unroll
            for (int nt = 0; nt < 4; ++nt) {
                size_t col = bn + wcol + nt * 16 + r;
#pragma unroll
                for (int i = 0; i < 4; ++i)
                    C[(row + i) * (size_t)ldc + col] = acc[mt][nt][i];
            }
        }
    } else if (MODE == 4) {
        u16* C = (u16*)Cv + (size_t)bz * sC;
#pragma unroll
        for (int mt = 0; mt < 4; ++mt) {
            size_t row = bm + wrow + mt * 16 + q * 4;
#pragma unroll
            for (int nt = 0; nt < 4; ++nt) {
                size_t col = bn + wcol + nt * 16 + r;
#pragma unroll
                for (int i = 0; i < 4; ++i)
                    C[(row + i) * (size_t)ldc + col] = f2h(acc[mt][nt][i]);
            }
        }
    } else {  // MODE 3: fused QKV epilogue, region uniform per block
        int region = blockIdx.y >> 3;                 // 0:Q 1:K 2:V
        if (region < 2) {
            u16* C = (u16*)Cv + (size_t)region * 16777216;  // Q or K [16384x1024]
            size_t cb = bn - (size_t)region * 1024;
#pragma unroll
            for (int mt = 0; mt < 4; ++mt) {
                size_t row = bm + wrow + mt * 16 + q * 4;
#pragma unroll
                for (int nt = 0; nt < 4; ++nt) {
                    size_t col = cb + wcol + nt * 16 + r;
#pragma unroll
                    for (int i = 0; i < 4; ++i)
                        C[(row + i) * 1024 + col] = f2bf(acc[mt][nt][i]);
                }
            }
        } else {
            // VT[b][d][t] = V[b*2048+t][d]; b = bm>>11 is BLOCK-UNIFORM
            // (128-row tiles never straddle the 2048-row batch boundary).
            // Each lane owns 4 consecutive t at fixed d -> one ushort4 store.
            u16* Cb = (u16*)Cv2 + (bm >> 11) * (size_t)(1024 * 2048)
                      + (bn - 2048) * 2048 + (bm & 2047)
                      + (size_t)(wcol + r) * 2048 + (wrow + q * 4);
#pragma unroll
            for (int nt = 0; nt < 4; ++nt) {
#pragma unroll
                for (int mt = 0; mt < 4; ++mt) {
                    ushort4 o;
                    o.x = f2bf(acc[mt][nt][0]);
                    o.y = f2bf(acc[mt][nt][1]);
                    o.z = f2bf(acc[mt][nt][2]);
                    o.w = f2bf(acc[mt][nt][3]);
                    *(ushort4*)(Cb + (size_t)(nt * 16) * 2048 + mt * 16) = o;
                }
            }
        }
    }
}

// ---- masked softmax, ONE ROW PER WAVE: fp16 row in, bf16 P in place (full row)
// Read and write both use us8 chunks: chunk c = j*64+lane covers cols c*8..c*8+7.
__global__ void softmax_rows_w(u16* __restrict__ E, const int* __restrict__ lengths) {
    int row  = blockIdx.x * 4 + (threadIdx.x >> 6);   // 16384 rows, 4 waves/block
    int lane = threadIdx.x & 63;
    int len  = lengths[row >> 11];
    u16* e = E + (size_t)row * 2048;

    float vals[32];
#pragma unroll
    for (int j = 0; j < 4; ++j) {
        us8 v = ((const us8*)e)[j * 64 + lane];
#pragma unroll
        for (int w = 0; w < 8; ++w) vals[j * 8 + w] = h2f(v[w]);
    }

    float m = -3.4e38f;
#pragma unroll
    for (int j = 0; j < 4; ++j) {
        int base = (j * 64 + lane) * 8;
#pragma unroll
        for (int w = 0; w < 8; ++w)
            if (base + w < len) m = fmaxf(m, vals[j * 8 + w]);
    }
#pragma unroll
    for (int off = 32; off; off >>= 1) m = fmaxf(m, __shfl_xor(m, off));

    const float C = 0.18033688011112042f;   // log2(e)/8  (scale 1/sqrt(64))
    float p[32]; float s = 0.f;
#pragma unroll
    for (int j = 0; j < 4; ++j) {
        int base = (j * 64 + lane) * 8;
#pragma unroll
        for (int w = 0; w < 8; ++w) {
            float v = (base + w < len) ? exp2f((vals[j * 8 + w] - m) * C) : 0.f;
            p[j * 8 + w] = v;
            s += v;
        }
    }
#pragma unroll
    for (int off = 32; off; off >>= 1) s += __shfl_xor(s, off);
    float rinv = 1.0f / s;

    // bf16 P over the fp16 row, identical chunk mapping as the read
#pragma unroll
    for (int j = 0; j < 4; ++j) {
        us8 o;
#pragma unroll
        for (int w = 0; w < 8; ++w) o[w] = f2bf(p[j * 8 + w] * rinv);
        ((us8*)e)[j * 64 + lane] = o;
    }
}

// ------------------------------------------------------------------ launch
extern "C" void kernel_launch(void* const* d_in, const int* in_sizes, int n_in,
                              void* d_out, int out_size, void* d_ws, size_t ws_size,
                              hipStream_t stream) {
    const float* x  = (const float*)d_in[0];
    const float* Wq = (const float*)d_in[1];
    const float* Wk = (const float*)d_in[2];
    const float* Wv = (const float*)d_in[3];
    float* out = (float*)d_out;
    char* ws = (char*)d_ws;

    const size_t SB  = 2097152;      // u16 elems per batch [2048x1024]
    const size_t SBe = 4194304;      // u16 elems per batch energy [2048x2048]

    // ws: lengths 256B | x16 32MB | WT 6MB | VT 32MB | E 64MB fp16 = 140,509,440 B
    if (ws_size < 140509440ULL) return;              // R3 proved >=207.6MB available
    int* lengths = (int*)ws;
    u16* x16 = (u16*)(ws + 256);
    u16* WT  = (u16*)(ws + 33554688);
    u16* VT  = (u16*)(ws + 39846144);
    u16* E   = (u16*)(ws + 73400576);
    u16* Qb  = (u16*)d_out;                          // Q,K parked in d_out (64 MiB)
    u16* Kb  = Qb + 16777216;

    cast_x<<<dim3(16384), dim3(256), 0, stream>>>(x, x16);
    transpose_cast_w<<<dim3(32, 32, 3), dim3(32, 8), 0, stream>>>(Wq, Wk, Wv, WT);
    calc_lengths<<<dim3(8), dim3(256), 0, stream>>>(x, lengths);

    // fused QKV: x16[16384x1024] @ WT[3072x1024]^T -> Q,K (d_out) + VT (ws)
    gemm_bt<3><<<dim3(128, 24, 1), 256, 0, stream>>>(x16, 1024, 0, WT, 1024, 0,
                                                     Qb, VT, 0, 0, 1024, lengths);

    // energy[b] = Q_b K_b^T -> fp16 E; blocks with bn >= len[b] skipped
    gemm_bt<4><<<dim3(16, 16, 8), 256, 0, stream>>>(Qb, 1024, SB, Kb, 1024, SB,
                                                    E, nullptr, 2048, SBe, 1024, lengths);

    // masked softmax -> bf16 P in place (one row per wave)
    softmax_rows_w<<<dim3(4096), dim3(256), 0, stream>>>(E, lengths);

    // out[b] = P_b V_b = P_b (VT_b)^T; K clamped to round32(len[b])
    gemm_bt<5><<<dim3(16, 8, 8), 256, 0, stream>>>(E, 2048, SBe, VT, 2048, SB,
                                                   out, nullptr, 1024, SB, 2048, lengths);
}